// Round 1
// baseline (204.812 us; speedup 1.0000x reference)
//
#include <hip/hip_runtime.h>

#define NBATCH 16
#define MAXB 256
#define BS 16
#define HQ 32
#define HKV 8
#define G 4
#define HD 128
#define SCALE 0.08838834764831845f
#define NEGF -1.0e30f

// Split kernel: grid.x = NBATCH*HKV*nwg, 256 threads (4 waves).
// Each wave = one partial (flash-decoding style split over kv positions).
__global__ __launch_bounds__(256) void pa_split(
    const float* __restrict__ q,
    const float* __restrict__ knew,
    const float* __restrict__ vnew,
    const float* __restrict__ k_cache,
    const float* __restrict__ v_cache,
    const int* __restrict__ block_tables,
    const int* __restrict__ seq_lens,
    float* __restrict__ part_ml,   // [B][HKV][P][G][2]
    float* __restrict__ part_acc,  // [B][HKV][P][G][HD]
    int nwg)
{
  const int wg    = blockIdx.x;
  const int split = wg % nwg;
  const int h     = (wg / nwg) % HKV;
  const int b     = wg / (nwg * HKV);
  const int wave  = threadIdx.x >> 6;
  const int lane  = threadIdx.x & 63;
  const int P     = nwg * 4;
  const int part  = split * 4 + wave;

  const int seq_len = seq_lens[b];
  const int cnt = (seq_len + P - 1) / P;
  const int s0  = part * cnt;
  const int s1  = min(seq_len, s0 + cnt);

  // q fragment: head = h*G + j, dims 2*lane, 2*lane+1
  float qr[G][2];
#pragma unroll
  for (int j = 0; j < G; ++j) {
    const float* qp = q + (size_t)(b * HQ + h * G + j) * HD + 2 * lane;
    qr[j][0] = qp[0];
    qr[j][1] = qp[1];
  }

  float m[G], l[G], a0[G], a1[G];
#pragma unroll
  for (int j = 0; j < G; ++j) { m[j] = NEGF; l[j] = 0.f; a0[j] = 0.f; a1[j] = 0.f; }

  const int last = seq_len - 1;
  for (int s = s0; s < s1; ++s) {
    const float *kp, *vp;
    if (s == last) {
      // the token being written this step lives in the q/k/v inputs,
      // exactly at logical position seq_len-1 (see slot_mapping derivation)
      kp = knew + (size_t)(b * HKV + h) * HD;
      vp = vnew + (size_t)(b * HKV + h) * HD;
    } else {
      const int blk = block_tables[b * MAXB + (s >> 4)];
      const size_t off = (((size_t)blk * BS + (s & 15)) * HKV + h) * HD;
      kp = k_cache + off;
      vp = v_cache + off;
    }
    const float2 kk = *(const float2*)(kp + 2 * lane);
    const float2 vv = *(const float2*)(vp + 2 * lane);

    float sc[G];
#pragma unroll
    for (int j = 0; j < G; ++j) {
      float p = qr[j][0] * kk.x + qr[j][1] * kk.y;
#pragma unroll
      for (int o = 32; o > 0; o >>= 1) p += __shfl_xor(p, o, 64);
      sc[j] = p * SCALE;
    }
#pragma unroll
    for (int j = 0; j < G; ++j) {
      const float mn = fmaxf(m[j], sc[j]);
      const float f  = __expf(m[j] - mn);   // exp(-1e30-x) underflows to 0 on first iter
      const float p  = __expf(sc[j] - mn);
      l[j]  = l[j] * f + p;
      a0[j] = a0[j] * f + p * vv.x;
      a1[j] = a1[j] * f + p * vv.y;
      m[j]  = mn;
    }
  }

  const size_t pidx = (size_t)(b * HKV + h) * P + part;
  if (lane == 0) {
#pragma unroll
    for (int j = 0; j < G; ++j) {
      part_ml[(pidx * G + j) * 2 + 0] = m[j];
      part_ml[(pidx * G + j) * 2 + 1] = l[j];
    }
  }
#pragma unroll
  for (int j = 0; j < G; ++j) {
    float2* ap = (float2*)(part_acc + (pidx * G + j) * HD + 2 * lane);
    *ap = make_float2(a0[j], a1[j]);
  }
}

// Reduce kernel: one block per (b, q-head), 128 threads (one per dim).
__global__ __launch_bounds__(128) void pa_reduce(
    const float* __restrict__ part_ml,
    const float* __restrict__ part_acc,
    float* __restrict__ out,
    int P)
{
  const int qh = blockIdx.x % HQ;
  const int b  = blockIdx.x / HQ;
  const int h  = qh >> 2;
  const int j  = qh & 3;
  const int d  = threadIdx.x;

  const size_t base = (size_t)(b * HKV + h) * P;
  float mg = NEGF;
  for (int p = 0; p < P; ++p)
    mg = fmaxf(mg, part_ml[((base + p) * G + j) * 2 + 0]);

  float lsum = 0.f, asum = 0.f;
  for (int p = 0; p < P; ++p) {
    const float mm = part_ml[((base + p) * G + j) * 2 + 0];
    const float ll = part_ml[((base + p) * G + j) * 2 + 1];
    const float f  = __expf(mm - mg);   // empty partial: ll==0 so no contribution
    lsum += f * ll;
    asum += f * part_acc[((base + p) * G + j) * HD + d];
  }
  out[(size_t)(b * HQ + qh) * HD + d] = asum / lsum;
}

extern "C" void kernel_launch(void* const* d_in, const int* in_sizes, int n_in,
                              void* d_out, int out_size, void* d_ws, size_t ws_size,
                              hipStream_t stream) {
  const float* q  = (const float*)d_in[0];
  const float* k  = (const float*)d_in[1];
  const float* v  = (const float*)d_in[2];
  const float* kc = (const float*)d_in[3];
  const float* vc = (const float*)d_in[4];
  // d_in[5] = slot_mapping (unused: derived == position seq_len-1)
  const int* bt = (const int*)d_in[6];
  const int* sl = (const int*)d_in[7];
  // d_in[8] = query_lens (all 1), d_in[9] = is_prefill (False) — unused

  int nwg = 8;
  for (;;) {
    const size_t need = (size_t)NBATCH * HKV * (nwg * 4) * G * (2 + HD) * sizeof(float);
    if (need <= ws_size || nwg == 1) break;
    nwg >>= 1;
  }
  const int P = nwg * 4;
  float* part_ml  = (float*)d_ws;
  float* part_acc = part_ml + (size_t)NBATCH * HKV * P * G * 2;

  hipLaunchKernelGGL(pa_split, dim3(NBATCH * HKV * nwg), dim3(256), 0, stream,
                     q, k, v, kc, vc, bt, sl, part_ml, part_acc, nwg);
  hipLaunchKernelGGL(pa_reduce, dim3(NBATCH * HQ), dim3(128), 0, stream,
                     part_ml, part_acc, (float*)d_out, P);
}

// Round 2
// 168.378 us; speedup vs baseline: 1.2164x; 1.2164x over previous
//
#include <hip/hip_runtime.h>

#define NBATCH 16
#define MAXB 256
#define BS 16
#define HQ 32
#define HKV 8
#define G 4
#define HD 128
#define SCALE 0.08838834764831845f
#define NEGF -1.0e30f

__device__ __forceinline__ float dot8(const float4 a0, const float4 a1,
                                      const float4 b0, const float4 b1) {
  return a0.x*b0.x + a0.y*b0.y + a0.z*b0.z + a0.w*b0.w +
         a1.x*b1.x + a1.y*b1.y + a1.z*b1.z + a1.w*b1.w;
}

// Workgroup = (b, split): 512 threads = 8 waves, wave h handles kv-head h.
// Lane layout: tg = lane>>4 (position subgroup, 4 positions in flight),
//              tl = lane&15 (dim group: dims [tl*8, tl*8+8)).
// The 8 waves together stream fully contiguous 4KB per position.
__global__ __launch_bounds__(512, 4) void pa_split(
    const float* __restrict__ q,
    const float* __restrict__ knew,
    const float* __restrict__ vnew,
    const float* __restrict__ k_cache,
    const float* __restrict__ v_cache,
    const int* __restrict__ block_tables,
    const int* __restrict__ seq_lens,
    float* __restrict__ part_ml,   // [B][HKV][P][G][2]
    float* __restrict__ part_acc,  // [B][HKV][P][G][HD]
    int nsplit)
{
  const int split = blockIdx.x % nsplit;
  const int b     = blockIdx.x / nsplit;
  const int h     = threadIdx.x >> 6;
  const int lane  = threadIdx.x & 63;
  const int tg    = lane >> 4;
  const int tl    = lane & 15;

  const int seq_len = seq_lens[b];
  int per = (seq_len + nsplit - 1) / nsplit;
  per = (per + 15) & ~15;             // chunk-align so block index is wave-uniform
  const int s0 = split * per;
  const int s1 = min(seq_len, s0 + per);
  const int last = seq_len - 1;

  float4 q0[G], q1[G];
#pragma unroll
  for (int j = 0; j < G; ++j) {
    const float* qp = q + (size_t)(b*HQ + h*G + j)*HD + tl*8;
    q0[j] = ((const float4*)qp)[0];
    q1[j] = ((const float4*)qp)[1];
  }

  float m[G], l[G];
  float4 a0[G], a1[G];
#pragma unroll
  for (int j = 0; j < G; ++j) {
    m[j] = NEGF; l[j] = 0.f;
    a0[j] = make_float4(0.f,0.f,0.f,0.f);
    a1[j] = make_float4(0.f,0.f,0.f,0.f);
  }

  const float* knp = knew + (size_t)(b*HKV + h)*HD + tl*8;
  const float* vnp = vnew + (size_t)(b*HKV + h)*HD + tl*8;

  for (int c = s0; c < s1; c += 16) {
    const int blk = block_tables[b*MAXB + (c >> 4)];
    const size_t base = ((size_t)blk*BS)*(HKV*HD) + (size_t)h*HD + tl*8;
#pragma unroll
    for (int i = 0; i < 4; ++i) {
      const int s = c + i*4 + tg;
      const bool valid = s < s1;
      const float* kp = k_cache + base + (size_t)(i*4 + tg)*(HKV*HD);
      const float* vp = v_cache + base + (size_t)(i*4 + tg)*(HKV*HD);
      if (s == last) { kp = knp; vp = vnp; }   // token written this step lives in k/v inputs
      const float4 k0 = ((const float4*)kp)[0];
      const float4 k1 = ((const float4*)kp)[1];
      const float4 v0 = ((const float4*)vp)[0];
      const float4 v1 = ((const float4*)vp)[1];

      float sc[G];
#pragma unroll
      for (int j = 0; j < G; ++j) {
        float p = dot8(q0[j], q1[j], k0, k1);
        p += __shfl_xor(p, 1, 64);
        p += __shfl_xor(p, 2, 64);
        p += __shfl_xor(p, 4, 64);
        p += __shfl_xor(p, 8, 64);
        sc[j] = valid ? p * SCALE : NEGF;
      }
#pragma unroll
      for (int j = 0; j < G; ++j) {
        const float mn = fmaxf(m[j], sc[j]);
        const float f  = __expf(m[j] - mn);
        const float pp = __expf(sc[j] - mn);
        l[j] = l[j]*f + pp;
        a0[j].x = a0[j].x*f + pp*v0.x;
        a0[j].y = a0[j].y*f + pp*v0.y;
        a0[j].z = a0[j].z*f + pp*v0.z;
        a0[j].w = a0[j].w*f + pp*v0.w;
        a1[j].x = a1[j].x*f + pp*v1.x;
        a1[j].y = a1[j].y*f + pp*v1.y;
        a1[j].z = a1[j].z*f + pp*v1.z;
        a1[j].w = a1[j].w*f + pp*v1.w;
        m[j] = mn;
      }
    }
  }

  // combine the 4 tg-subgroup partials (butterfly over xor 16, 32)
#pragma unroll
  for (int mask = 16; mask <= 32; mask <<= 1) {
#pragma unroll
    for (int j = 0; j < G; ++j) {
      const float mo = __shfl_xor(m[j], mask, 64);
      const float lo = __shfl_xor(l[j], mask, 64);
      const float mn = fmaxf(m[j], mo);
      const float f0 = __expf(m[j] - mn);
      const float f1 = __expf(mo  - mn);
      l[j] = l[j]*f0 + lo*f1;
      float t;
      t = __shfl_xor(a0[j].x, mask, 64); a0[j].x = a0[j].x*f0 + t*f1;
      t = __shfl_xor(a0[j].y, mask, 64); a0[j].y = a0[j].y*f0 + t*f1;
      t = __shfl_xor(a0[j].z, mask, 64); a0[j].z = a0[j].z*f0 + t*f1;
      t = __shfl_xor(a0[j].w, mask, 64); a0[j].w = a0[j].w*f0 + t*f1;
      t = __shfl_xor(a1[j].x, mask, 64); a1[j].x = a1[j].x*f0 + t*f1;
      t = __shfl_xor(a1[j].y, mask, 64); a1[j].y = a1[j].y*f0 + t*f1;
      t = __shfl_xor(a1[j].z, mask, 64); a1[j].z = a1[j].z*f0 + t*f1;
      t = __shfl_xor(a1[j].w, mask, 64); a1[j].w = a1[j].w*f0 + t*f1;
      m[j] = mn;
    }
  }

  if (tg == 0) {
    const size_t pidx = (size_t)(b*HKV + h)*nsplit + split;
    if (tl == 0) {
#pragma unroll
      for (int j = 0; j < G; ++j) {
        part_ml[(pidx*G + j)*2 + 0] = m[j];
        part_ml[(pidx*G + j)*2 + 1] = l[j];
      }
    }
#pragma unroll
    for (int j = 0; j < G; ++j) {
      float4* ap = (float4*)(part_acc + (pidx*G + j)*HD + tl*8);
      ap[0] = a0[j];
      ap[1] = a1[j];
    }
  }
}

// Reduce: one block per (b, q-head), 128 threads (one per dim).
__global__ __launch_bounds__(128) void pa_reduce(
    const float* __restrict__ part_ml,
    const float* __restrict__ part_acc,
    float* __restrict__ out,
    int P)
{
  const int qh = blockIdx.x % HQ;
  const int b  = blockIdx.x / HQ;
  const int h  = qh >> 2;
  const int j  = qh & 3;
  const int d  = threadIdx.x;

  const size_t base = (size_t)(b*HKV + h) * P;
  float mg = NEGF;
  for (int p = 0; p < P; ++p)
    mg = fmaxf(mg, part_ml[((base + p)*G + j)*2 + 0]);

  float lsum = 0.f, asum = 0.f;
  for (int p = 0; p < P; ++p) {
    const float mm = part_ml[((base + p)*G + j)*2 + 0];
    const float ll = part_ml[((base + p)*G + j)*2 + 1];
    const float f  = __expf(mm - mg);   // empty partial: ll==0, acc==0
    lsum += f * ll;
    asum += f * part_acc[((base + p)*G + j)*HD + d];
  }
  out[(size_t)(b*HQ + qh)*HD + d] = asum / lsum;
}

extern "C" void kernel_launch(void* const* d_in, const int* in_sizes, int n_in,
                              void* d_out, int out_size, void* d_ws, size_t ws_size,
                              hipStream_t stream) {
  const float* q  = (const float*)d_in[0];
  const float* k  = (const float*)d_in[1];
  const float* v  = (const float*)d_in[2];
  const float* kc = (const float*)d_in[3];
  const float* vc = (const float*)d_in[4];
  // d_in[5] = slot_mapping (unused: it addresses logical position seq_len-1)
  const int* bt = (const int*)d_in[6];
  const int* sl = (const int*)d_in[7];
  // d_in[8] = query_lens (all 1), d_in[9] = is_prefill (False) — unused

  int nsplit = 32;
  for (;;) {
    const size_t need = (size_t)NBATCH * HKV * nsplit * G * (2 + HD) * sizeof(float);
    if (need <= ws_size || nsplit == 1) break;
    nsplit >>= 1;
  }
  float* part_ml  = (float*)d_ws;
  float* part_acc = part_ml + (size_t)NBATCH * HKV * nsplit * G * 2;

  hipLaunchKernelGGL(pa_split, dim3(NBATCH * nsplit), dim3(512), 0, stream,
                     q, k, v, kc, vc, bt, sl, part_ml, part_acc, nsplit);
  hipLaunchKernelGGL(pa_reduce, dim3(NBATCH * HQ), dim3(128), 0, stream,
                     part_ml, part_acc, (float*)d_out, nsplit);
}

// Round 3
// 149.039 us; speedup vs baseline: 1.3742x; 1.1298x over previous
//
#include <hip/hip_runtime.h>

#define NBATCH 16
#define MAXB 256
#define BS 16
#define HQ 32
#define HKV 8
#define G 4
#define HD 128
#define SCALE 0.08838834764831845f
#define NEGF -1.0e30f

__device__ __forceinline__ float dot8(const float4 a0, const float4 a1,
                                      const float4 b0, const float4 b1) {
  return a0.x*b0.x + a0.y*b0.y + a0.z*b0.z + a0.w*b0.w +
         a1.x*b1.x + a1.y*b1.y + a1.z*b1.z + a1.w*b1.w;
}

// Workgroup = (b, split): 512 threads = 8 waves, wave h handles kv-head h.
// Lane layout: tg = lane>>4 (position subgroup, 4 positions in flight),
//              tl = lane&15 (dim group: dims [tl*8, tl*8+8)).
// The 8 waves together stream fully contiguous 4KB per position.
// __launch_bounds__(512,2): cap VGPR at ~128 so the ~110-reg live set
// (q 32 + acc 32 + m/l 8 + transients) does NOT spill (r2: (512,4) -> 64 VGPR
// -> 106MB scratch writes). 2 blocks/CU = 16 waves/CU.
__global__ __launch_bounds__(512, 2) void pa_split(
    const float* __restrict__ q,
    const float* __restrict__ knew,
    const float* __restrict__ vnew,
    const float* __restrict__ k_cache,
    const float* __restrict__ v_cache,
    const int* __restrict__ block_tables,
    const int* __restrict__ seq_lens,
    float* __restrict__ part_ml,   // [B][HKV][P][G][2]
    float* __restrict__ part_acc,  // [B][HKV][P][G][HD]
    int nsplit)
{
  const int split = blockIdx.x % nsplit;
  const int b     = blockIdx.x / nsplit;
  const int h     = threadIdx.x >> 6;
  const int lane  = threadIdx.x & 63;
  const int tg    = lane >> 4;
  const int tl    = lane & 15;

  const int seq_len = seq_lens[b];
  int per = (seq_len + nsplit - 1) / nsplit;
  per = (per + 15) & ~15;             // chunk-align so block index is wave-uniform
  const int s0 = split * per;
  const int s1 = min(seq_len, s0 + per);
  const int last = seq_len - 1;

  float4 q0[G], q1[G];
#pragma unroll
  for (int j = 0; j < G; ++j) {
    const float* qp = q + (size_t)(b*HQ + h*G + j)*HD + tl*8;
    q0[j] = ((const float4*)qp)[0];
    q1[j] = ((const float4*)qp)[1];
  }

  float m[G], l[G];
  float4 a0[G], a1[G];
#pragma unroll
  for (int j = 0; j < G; ++j) {
    m[j] = NEGF; l[j] = 0.f;
    a0[j] = make_float4(0.f,0.f,0.f,0.f);
    a1[j] = make_float4(0.f,0.f,0.f,0.f);
  }

  const float* knp = knew + (size_t)(b*HKV + h)*HD + tl*8;
  const float* vnp = vnew + (size_t)(b*HKV + h)*HD + tl*8;

  for (int c = s0; c < s1; c += 16) {
    const int blk = block_tables[b*MAXB + (c >> 4)];
    const size_t base = ((size_t)blk*BS)*(HKV*HD) + (size_t)h*HD + tl*8;
#pragma unroll
    for (int i = 0; i < 4; ++i) {
      const int s = c + i*4 + tg;
      const bool valid = s < s1;
      const float* kp = k_cache + base + (size_t)(i*4 + tg)*(HKV*HD);
      const float* vp = v_cache + base + (size_t)(i*4 + tg)*(HKV*HD);
      if (s == last) { kp = knp; vp = vnp; }   // token written this step lives in k/v inputs
      const float4 k0 = ((const float4*)kp)[0];
      const float4 k1 = ((const float4*)kp)[1];
      const float4 v0 = ((const float4*)vp)[0];
      const float4 v1 = ((const float4*)vp)[1];

      float sc[G];
#pragma unroll
      for (int j = 0; j < G; ++j) {
        float p = dot8(q0[j], q1[j], k0, k1);
        p += __shfl_xor(p, 1, 64);
        p += __shfl_xor(p, 2, 64);
        p += __shfl_xor(p, 4, 64);
        p += __shfl_xor(p, 8, 64);
        sc[j] = valid ? p * SCALE : NEGF;
      }
#pragma unroll
      for (int j = 0; j < G; ++j) {
        const float mn = fmaxf(m[j], sc[j]);
        const float f  = __expf(m[j] - mn);
        const float pp = __expf(sc[j] - mn);
        l[j] = l[j]*f + pp;
        a0[j].x = a0[j].x*f + pp*v0.x;
        a0[j].y = a0[j].y*f + pp*v0.y;
        a0[j].z = a0[j].z*f + pp*v0.z;
        a0[j].w = a0[j].w*f + pp*v0.w;
        a1[j].x = a1[j].x*f + pp*v1.x;
        a1[j].y = a1[j].y*f + pp*v1.y;
        a1[j].z = a1[j].z*f + pp*v1.z;
        a1[j].w = a1[j].w*f + pp*v1.w;
        m[j] = mn;
      }
    }
  }

  // combine the 4 tg-subgroup partials (butterfly over xor 16, 32).
  // Lanes whose positions were all invalid carry m=NEGF -> weight exp(NEGF-mn)=0.
#pragma unroll
  for (int mask = 16; mask <= 32; mask <<= 1) {
#pragma unroll
    for (int j = 0; j < G; ++j) {
      const float mo = __shfl_xor(m[j], mask, 64);
      const float lo = __shfl_xor(l[j], mask, 64);
      const float mn = fmaxf(m[j], mo);
      const float f0 = __expf(m[j] - mn);
      const float f1 = __expf(mo  - mn);
      l[j] = l[j]*f0 + lo*f1;
      float t;
      t = __shfl_xor(a0[j].x, mask, 64); a0[j].x = a0[j].x*f0 + t*f1;
      t = __shfl_xor(a0[j].y, mask, 64); a0[j].y = a0[j].y*f0 + t*f1;
      t = __shfl_xor(a0[j].z, mask, 64); a0[j].z = a0[j].z*f0 + t*f1;
      t = __shfl_xor(a0[j].w, mask, 64); a0[j].w = a0[j].w*f0 + t*f1;
      t = __shfl_xor(a1[j].x, mask, 64); a1[j].x = a1[j].x*f0 + t*f1;
      t = __shfl_xor(a1[j].y, mask, 64); a1[j].y = a1[j].y*f0 + t*f1;
      t = __shfl_xor(a1[j].z, mask, 64); a1[j].z = a1[j].z*f0 + t*f1;
      t = __shfl_xor(a1[j].w, mask, 64); a1[j].w = a1[j].w*f0 + t*f1;
      m[j] = mn;
    }
  }

  if (tg == 0) {
    const size_t pidx = (size_t)(b*HKV + h)*nsplit + split;
    if (tl == 0) {
#pragma unroll
      for (int j = 0; j < G; ++j) {
        part_ml[(pidx*G + j)*2 + 0] = m[j];
        part_ml[(pidx*G + j)*2 + 1] = l[j];
      }
    }
#pragma unroll
    for (int j = 0; j < G; ++j) {
      float4* ap = (float4*)(part_acc + (pidx*G + j)*HD + tl*8);
      ap[0] = a0[j];
      ap[1] = a1[j];
    }
  }
}

// Reduce: one block per (b, q-head), 128 threads (one per dim).
__global__ __launch_bounds__(128) void pa_reduce(
    const float* __restrict__ part_ml,
    const float* __restrict__ part_acc,
    float* __restrict__ out,
    int P)
{
  const int qh = blockIdx.x % HQ;
  const int b  = blockIdx.x / HQ;
  const int h  = qh >> 2;
  const int j  = qh & 3;
  const int d  = threadIdx.x;

  const size_t base = (size_t)(b*HKV + h) * P;
  float mg = NEGF;
  for (int p = 0; p < P; ++p)
    mg = fmaxf(mg, part_ml[((base + p)*G + j)*2 + 0]);

  float lsum = 0.f, asum = 0.f;
  for (int p = 0; p < P; ++p) {
    const float mm = part_ml[((base + p)*G + j)*2 + 0];
    const float ll = part_ml[((base + p)*G + j)*2 + 1];
    const float f  = __expf(mm - mg);   // empty partial: ll==0, acc==0
    lsum += f * ll;
    asum += f * part_acc[((base + p)*G + j)*HD + d];
  }
  out[(size_t)(b*HQ + qh)*HD + d] = asum / lsum;
}

extern "C" void kernel_launch(void* const* d_in, const int* in_sizes, int n_in,
                              void* d_out, int out_size, void* d_ws, size_t ws_size,
                              hipStream_t stream) {
  const float* q  = (const float*)d_in[0];
  const float* k  = (const float*)d_in[1];
  const float* v  = (const float*)d_in[2];
  const float* kc = (const float*)d_in[3];
  const float* vc = (const float*)d_in[4];
  // d_in[5] = slot_mapping (unused: it addresses logical position seq_len-1)
  const int* bt = (const int*)d_in[6];
  const int* sl = (const int*)d_in[7];
  // d_in[8] = query_lens (all 1), d_in[9] = is_prefill (False) — unused

  int nsplit = 32;
  for (;;) {
    const size_t need = (size_t)NBATCH * HKV * nsplit * G * (2 + HD) * sizeof(float);
    if (need <= ws_size || nsplit == 1) break;
    nsplit >>= 1;
  }
  float* part_ml  = (float*)d_ws;
  float* part_acc = part_ml + (size_t)NBATCH * HKV * nsplit * G * 2;

  hipLaunchKernelGGL(pa_split, dim3(NBATCH * nsplit), dim3(512), 0, stream,
                     q, k, v, kc, vc, bt, sl, part_ml, part_acc, nsplit);
  hipLaunchKernelGGL(pa_reduce, dim3(NBATCH * HQ), dim3(128), 0, stream,
                     part_ml, part_acc, (float*)d_out, nsplit);
}